// Round 9
// baseline (31.662 us; speedup 1.0000x reference)
//
#include <hip/hip_runtime.h>
#include <math.h>

// Effective math (cross-attn K/V rows identical per batch element ->
// softmax uniform -> ctx == v; self-attn and QK paths are dead):
//   x   = im_repr @ ca_wv + ca_bv                  [256,768]
//   h   = gelu(x @ fi_w1 + fi_b1)  (exact erf)     [256,256]
//   y   = x + h @ fi_w2 + fi_b2                    [256,768]
//   out = LN(y) * ln_g + ln_b
//
// Round-8: row-local single main kernel + one-time bf16 pack.
//  kcvt : wv/w1/w2 -> k-pair-packed bf16 in ws (1 MB total, L2-resident)
//  kmain: 256 blocks (1 row each) x 768 thr; x->h->y->LN entirely in
//         LDS/registers; every 4B load = 2 weights = 2 FMAs.

#define DMODEL 768
#define ENCD   128
#define HID    256

// ws layout (uint32 elements)
#define WVP_OFF 0              // [64][768]   pairs along e
#define W1P_OFF 49152          // [384][256]  pairs along k
#define W2P_OFF 147456         // [128][768]  pairs along k
#define WS_UINTS 245760        // 983040 bytes

__device__ __forceinline__ unsigned short f2bf(float f) {
    unsigned u = __float_as_uint(f);
    u = (u + 0x7FFFu + ((u >> 16) & 1u)) >> 16;   // RNE
    return (unsigned short)u;
}
__device__ __forceinline__ float bflo(unsigned u) { return __uint_as_float(u << 16); }
__device__ __forceinline__ float bfhi(unsigned u) { return __uint_as_float(u & 0xFFFF0000u); }
__device__ __forceinline__ unsigned packbf(float a, float b) {
    return (unsigned)f2bf(a) | ((unsigned)f2bf(b) << 16);
}

// ---- kcvt: grid(960) x 256 thr, one packed uint per thread ----
__global__ __launch_bounds__(256) void kcvt(
    const float* __restrict__ wv,   // [128,768]
    const float* __restrict__ w1,   // [768,256]
    const float* __restrict__ w2,   // [256,768]
    unsigned* __restrict__ ws)
{
    const int gid = blockIdx.x * 256 + threadIdx.x;
    if (gid < 49152) {                      // wvp[e2][c]
        const int e2 = gid / DMODEL, c = gid % DMODEL;
        ws[WVP_OFF + gid] =
            packbf(wv[(2 * e2) * DMODEL + c], wv[(2 * e2 + 1) * DMODEL + c]);
    } else if (gid < 49152 + 98304) {       // w1p[k2][j]
        const int idx = gid - 49152;
        const int k2 = idx / HID, j = idx % HID;
        ws[W1P_OFF + idx] =
            packbf(w1[(2 * k2) * HID + j], w1[(2 * k2 + 1) * HID + j]);
    } else {                                // w2p[k2][c]
        const int idx = gid - 147456;
        const int k2 = idx / DMODEL, c = idx % DMODEL;
        ws[W2P_OFF + idx] =
            packbf(w2[(2 * k2) * DMODEL + c], w2[(2 * k2 + 1) * DMODEL + c]);
    }
}

// ---- kmain: grid(256 rows) x 768 thr ----
__global__ __launch_bounds__(768) void kmain(
    const float* __restrict__ im,   // [256,128]
    const float* __restrict__ bv,   // [768]
    const float* __restrict__ b1,   // [256]
    const float* __restrict__ b2,   // [768]
    const float* __restrict__ gam,  // [768]
    const float* __restrict__ bet,  // [768]
    const unsigned* __restrict__ ws,
    float* __restrict__ out)        // [256,768]
{
    __shared__ float im_s[ENCD];
    __shared__ float x_s[DMODEL];
    __shared__ float ph[3][HID];
    __shared__ float h_s[HID];
    __shared__ float red[12][2];

    const int t = threadIdx.x, r = blockIdx.x;

    if (t < ENCD) im_s[t] = im[r * ENCD + t];
    __syncthreads();

    // ---- phase 1: x[t] = im_row . wv[:,t] + bv[t]  (64 packed loads) ----
    float xa = 0.f, xb = 0.f;
    const unsigned* wvp = ws + WVP_OFF;
    #pragma unroll 8
    for (int e2 = 0; e2 < ENCD / 2; ++e2) {
        unsigned u = wvp[e2 * DMODEL + t];
        xa += im_s[2 * e2]     * bflo(u);
        xb += im_s[2 * e2 + 1] * bfhi(u);
    }
    const float x = xa + xb + bv[t];
    x_s[t] = x;
    __syncthreads();

    // ---- phase 2: split-K 3-way partials of x @ w1 ----
    {
        const int g = t >> 8, j = t & 255;
        const unsigned* w1p = ws + W1P_OFF;
        float c0 = 0.f, c1 = 0.f;
        #pragma unroll 8
        for (int k2 = g * 128; k2 < g * 128 + 128; ++k2) {
            unsigned u = w1p[k2 * HID + j];
            c0 += x_s[2 * k2]     * bflo(u);
            c1 += x_s[2 * k2 + 1] * bfhi(u);
        }
        ph[g][j] = c0 + c1;
    }
    __syncthreads();
    if (t < HID) {
        float v = ph[0][t] + ph[1][t] + ph[2][t] + b1[t];
        h_s[t] = 0.5f * v * (1.f + erff(v * 0.70710678118654752f));
    }
    __syncthreads();

    // ---- phase 3: y[t] = x[t] + h . w2[:,t] + b2[t]  (128 packed loads) ----
    float d0 = 0.f, d1 = 0.f;
    const unsigned* w2p = ws + W2P_OFF;
    #pragma unroll 8
    for (int k2 = 0; k2 < HID / 2; ++k2) {
        unsigned u = w2p[k2 * DMODEL + t];
        d0 += h_s[2 * k2]     * bflo(u);
        d1 += h_s[2 * k2 + 1] * bfhi(u);
    }
    const float y = x + b2[t] + (d0 + d1);

    // ---- phase 4: LayerNorm across 12 waves ----
    float s = y, q = y * y;
    #pragma unroll
    for (int off = 32; off > 0; off >>= 1) {
        s += __shfl_down(s, off);
        q += __shfl_down(q, off);
    }
    const int lane = t & 63, wave = t >> 6;
    if (lane == 0) { red[wave][0] = s; red[wave][1] = q; }
    __syncthreads();

    float ss = 0.f, qq = 0.f;
    #pragma unroll
    for (int w = 0; w < 12; ++w) { ss += red[w][0]; qq += red[w][1]; }
    const float mu   = ss * (1.f / DMODEL);
    const float rstd = rsqrtf(qq * (1.f / DMODEL) - mu * mu + 1e-12f);

    out[r * DMODEL + t] = (y - mu) * rstd * gam[t] + bet[t];
}

extern "C" void kernel_launch(void* const* d_in, const int* in_sizes, int n_in,
                              void* d_out, int out_size, void* d_ws, size_t ws_size,
                              hipStream_t stream) {
    const float* im  = (const float*)d_in[0];   // im_repr [256,128]
    const float* wv  = (const float*)d_in[13];  // ca_wv   [128,768]
    const float* bv  = (const float*)d_in[14];  // ca_bv   [768]
    const float* w1  = (const float*)d_in[16];  // fi_w1   [768,256]
    const float* b1  = (const float*)d_in[17];  // fi_b1   [256]
    const float* w2  = (const float*)d_in[18];  // fi_w2   [256,768]
    const float* b2  = (const float*)d_in[19];  // fi_b2   [768]
    const float* g   = (const float*)d_in[20];  // ln_g    [768]
    const float* bt  = (const float*)d_in[21];  // ln_b    [768]
    float* out = (float*)d_out;
    unsigned* ws = (unsigned*)d_ws;

    kcvt <<<dim3(960), 256, 0, stream>>>(wv, w1, w2, ws);
    kmain<<<dim3(256), 768, 0, stream>>>(im, bv, b1, b2, g, bt, ws, out);
}

// Round 10
// 28.535 us; speedup vs baseline: 1.1096x; 1.1096x over previous
//
#include <hip/hip_runtime.h>
#include <math.h>

// Effective math (cross-attn K/V rows identical per batch element ->
// softmax uniform -> ctx == v; self-attn and QK paths are dead):
//   x   = im_repr @ ca_wv + ca_bv                  [256,768]
//   h   = gelu(x @ fi_w1 + fi_b1)  (exact erf)     [256,256]
//   y   = x + h @ fi_w2 + fi_b2                    [256,768]
//   out = LN(y) * ln_g + ln_b
//
// Round-9: revert bf16. Rebalance per-CU bytes across 3 kernels:
//  kA: grid(6 kc, 64 rowquads) x 256 thr  — x slice + w1 partial (~220 KB/blk)
//  kB: grid(4 colslices, 64 rowquads) x 256 thr — h + y via float4 w2
//      (192 KB w2 per block, ALL 256 CUs busy; was 768 KB on 128 blocks)
//  kC: grid(256 rows) x 256 thr — LayerNorm only (~1.5 MB total)

#define DMODEL 768
#define ENCD   128
#define HID    256
#define KW     128   // kA k-slice width

// ws layout (float elements)
#define WS_X 0                      // x [256][768]
#define WS_P 196608                 // p [6][256][256]
#define WS_Y 589824                 // y [256][768]

__device__ __forceinline__ float gelu_exact(float v) {
    return 0.5f * v * (1.f + erff(v * 0.70710678118654752f));
}

// ---- kA: x col-slice (k=128 over im@wv) -> LDS -> w1 partial, 4 rows ----
__global__ __launch_bounds__(256) void kA(
    const float* __restrict__ im,   // [256,128]
    const float* __restrict__ wv,   // [128,768]
    const float* __restrict__ bv,   // [768]
    const float* __restrict__ w1,   // [768,256]
    float* __restrict__ ws)
{
    __shared__ float im_s[4][ENCD];
    __shared__ float x_s[4][KW];
    const int t  = threadIdx.x;
    const int kc = blockIdx.x;
    const int r0 = blockIdx.y * 4;

    #pragma unroll
    for (int i = t; i < 4 * ENCD; i += 256)
        im_s[i >> 7][i & 127] = im[(r0 + (i >> 7)) * ENCD + (i & 127)];
    __syncthreads();

    // stage 1: thread (half, c) computes rows {2*half, 2*half+1} at col c
    const int half = t >> 7, c = t & 127;
    const int col  = kc * KW + c;
    {
        const int ra = 2 * half, rb = ra + 1;
        float a0 = 0.f, a1 = 0.f;
        #pragma unroll 16
        for (int e = 0; e < ENCD; ++e) {
            float w = wv[e * DMODEL + col];
            a0 += im_s[ra][e] * w;
            a1 += im_s[rb][e] * w;
        }
        float b = bv[col];
        a0 += b; a1 += b;
        ws[WS_X + (r0 + ra) * DMODEL + col] = a0;
        ws[WS_X + (r0 + rb) * DMODEL + col] = a1;
        x_s[ra][c] = a0;
        x_s[rb][c] = a1;
    }
    __syncthreads();

    // stage 2: j = t, 4 rows share each w1 load (4 chains)
    {
        float c0 = 0.f, c1 = 0.f, c2 = 0.f, c3 = 0.f;
        const float* w1c = w1 + kc * KW * HID;
        #pragma unroll 16
        for (int k = 0; k < KW; ++k) {
            float w = w1c[k * HID + t];
            c0 += x_s[0][k] * w;
            c1 += x_s[1][k] * w;
            c2 += x_s[2][k] * w;
            c3 += x_s[3][k] * w;
        }
        float* p = ws + WS_P + kc * (256 * HID);
        p[(r0 + 0) * HID + t] = c0;
        p[(r0 + 1) * HID + t] = c1;
        p[(r0 + 2) * HID + t] = c2;
        p[(r0 + 3) * HID + t] = c3;
    }
}

// ---- kB: grid(4 colslices, 64 rowquads) x 256 thr ----
// h = gelu(sum p + b1) for 4 rows; y-slice = x + h @ w2[:,cols] + b2
__global__ __launch_bounds__(256) void kB(
    const float* __restrict__ b1,   // [256]
    const float* __restrict__ w2,   // [256,768]
    const float* __restrict__ b2,   // [768]
    float* __restrict__ ws)
{
    __shared__ float h_s[4][HID + 4];
    const int t  = threadIdx.x;
    const int cx = blockIdx.x;
    const int r0 = blockIdx.y * 4;

    // h for 4 rows: thread t computes h_s[ii][t]
    {
        const float* p = ws + WS_P;
        #pragma unroll
        for (int ii = 0; ii < 4; ++ii) {
            float v = b1[t];
            #pragma unroll
            for (int kc = 0; kc < 6; ++kc)
                v += p[kc * (256 * HID) + (r0 + ii) * HID + t];
            h_s[ii][t] = gelu_exact(v);
        }
    }
    __syncthreads();

    // y slice: 192 threads = 4 rows x 48 float4 col-groups
    if (t < 192) {
        const int rr  = t / 48;
        const int cg  = t % 48;
        const int col = cx * 192 + 4 * cg;

        float4 acc = *(const float4*)(b2 + col);
        #pragma unroll 8
        for (int j = 0; j < HID; ++j) {
            float hv = h_s[rr][j];
            float4 w = *(const float4*)(w2 + j * DMODEL + col);
            acc.x += hv * w.x; acc.y += hv * w.y;
            acc.z += hv * w.z; acc.w += hv * w.w;
        }
        const float4 xv = *(const float4*)(ws + WS_X + (r0 + rr) * DMODEL + col);
        float4 yv;
        yv.x = xv.x + acc.x; yv.y = xv.y + acc.y;
        yv.z = xv.z + acc.z; yv.w = xv.w + acc.w;
        *(float4*)(ws + WS_Y + (r0 + rr) * DMODEL + col) = yv;
    }
}

// ---- kC: LayerNorm. grid(256 rows) x 256 thr ----
__global__ __launch_bounds__(256) void kC(
    const float* __restrict__ gam, const float* __restrict__ bet,
    const float* __restrict__ ws, float* __restrict__ out)
{
    __shared__ float red[4][2];
    const int t = threadIdx.x, r = blockIdx.x;
    const float* y = ws + WS_Y + r * DMODEL;

    float v0 = y[t], v1 = y[t + 256], v2 = y[t + 512];
    float s = v0 + v1 + v2;
    float q = v0 * v0 + v1 * v1 + v2 * v2;
    #pragma unroll
    for (int off = 32; off > 0; off >>= 1) {
        s += __shfl_down(s, off);
        q += __shfl_down(q, off);
    }
    const int lane = t & 63, wave = t >> 6;
    if (lane == 0) { red[wave][0] = s; red[wave][1] = q; }
    __syncthreads();
    float ss = red[0][0] + red[1][0] + red[2][0] + red[3][0];
    float qq = red[0][1] + red[1][1] + red[2][1] + red[3][1];
    float mu   = ss * (1.f / DMODEL);
    float rstd = rsqrtf(qq * (1.f / DMODEL) - mu * mu + 1e-12f);

    out[r * DMODEL + t]       = (v0 - mu) * rstd * gam[t]       + bet[t];
    out[r * DMODEL + t + 256] = (v1 - mu) * rstd * gam[t + 256] + bet[t + 256];
    out[r * DMODEL + t + 512] = (v2 - mu) * rstd * gam[t + 512] + bet[t + 512];
}

extern "C" void kernel_launch(void* const* d_in, const int* in_sizes, int n_in,
                              void* d_out, int out_size, void* d_ws, size_t ws_size,
                              hipStream_t stream) {
    const float* im  = (const float*)d_in[0];   // im_repr [256,128]
    const float* wv  = (const float*)d_in[13];  // ca_wv   [128,768]
    const float* bv  = (const float*)d_in[14];  // ca_bv   [768]
    const float* w1  = (const float*)d_in[16];  // fi_w1   [768,256]
    const float* b1  = (const float*)d_in[17];  // fi_b1   [256]
    const float* w2  = (const float*)d_in[18];  // fi_w2   [256,768]
    const float* b2  = (const float*)d_in[19];  // fi_b2   [768]
    const float* g   = (const float*)d_in[20];  // ln_g    [768]
    const float* bt  = (const float*)d_in[21];  // ln_b    [768]
    float* out = (float*)d_out;
    float* ws  = (float*)d_ws;

    kA<<<dim3(6, 64),  256, 0, stream>>>(im, wv, bv, w1, ws);
    kB<<<dim3(4, 64),  256, 0, stream>>>(b1, w2, b2, ws);
    kC<<<dim3(256),    256, 0, stream>>>(g, bt, ws, out);
}